// Round 1
// baseline (1692.509 us; speedup 1.0000x reference)
//
#include <hip/hip_runtime.h>
#include <hip/hip_bf16.h>

#define N_NODES 50000
#define N_EDGES 800000
#define HDIM 128
#define NCH 5

typedef float f4 __attribute__((ext_vector_type(4)));

struct __align__(8) b16x4 { __hip_bfloat16 v[4]; };

// ---------------- CSR build ----------------

__global__ void k_count(const int* __restrict__ dst, int* __restrict__ cnt) {
  int i = blockIdx.x * blockDim.x + threadIdx.x;
  if (i < N_EDGES) atomicAdd(&cnt[dst[i]], 1);
}

__global__ void k_scan(const int* __restrict__ cnt, int* __restrict__ row,
                       int* __restrict__ cur) {
  __shared__ int buf[256];
  int tid = threadIdx.x;
  int run = 0;
  for (int base = 0; base < N_NODES; base += 256) {
    int i = base + tid;
    int v = (i < N_NODES) ? cnt[i] : 0;
    buf[tid] = v;
    __syncthreads();
    for (int off = 1; off < 256; off <<= 1) {
      int t = (tid >= off) ? buf[tid - off] : 0;
      __syncthreads();
      buf[tid] += t;
      __syncthreads();
    }
    if (i < N_NODES) {
      int excl = run + buf[tid] - v;
      row[i] = excl;
      cur[i] = excl;
    }
    run += buf[255];
    __syncthreads();
  }
  if (tid == 0) row[N_NODES] = run;
}

__global__ void k_scatter(const int* __restrict__ src, const int* __restrict__ dst,
                          int* __restrict__ cur, int* __restrict__ eid,
                          int* __restrict__ esrc) {
  int i = blockIdx.x * blockDim.x + threadIdx.x;
  if (i < N_EDGES) {
    int d = dst[i];
    int p = atomicAdd(&cur[d], 1);
    eid[p] = i;
    esrc[p] = src[i];
  }
}

// ---------------- shared 4x4-tile GEMM phase (32 rows x 128 cols, K=128) -------
// in: LDS [32][129] row-major (pad 129 keeps as[r][k] scalar reads conflict-free)
// wmat: row-major [128][128] streamed from global (L1/L2 resident)

__device__ __forceinline__ void tile_gemm(const float (*in)[129],
                                          const float* __restrict__ wmat,
                                          const float* __restrict__ bias,
                                          int r4, int jb, float acc[4][4]) {
  f4 bv = *reinterpret_cast<const f4*>(&bias[jb]);
#pragma unroll
  for (int ii = 0; ii < 4; ++ii)
#pragma unroll
    for (int jj = 0; jj < 4; ++jj) acc[ii][jj] = bv[jj];
#pragma unroll 4
  for (int k = 0; k < HDIM; ++k) {
    f4 wv = *reinterpret_cast<const f4*>(&wmat[k * HDIM + jb]);
    float a0 = in[r4 + 0][k];
    float a1 = in[r4 + 1][k];
    float a2 = in[r4 + 2][k];
    float a3 = in[r4 + 3][k];
#pragma unroll
    for (int jj = 0; jj < 4; ++jj) {
      acc[0][jj] += a0 * wv[jj];
      acc[1][jj] += a1 * wv[jj];
      acc[2][jj] += a2 * wv[jj];
      acc[3][jj] += a3 * wv[jj];
    }
  }
}

// ---------------- node embedding: h = relu(z@w0a+b0a)@w0b + b0b ----------------

__global__ __launch_bounds__(256) void k_node_emb(
    const float* __restrict__ z, const float* __restrict__ w0a,
    const float* __restrict__ b0a, const float* __restrict__ w0b,
    const float* __restrict__ b0b, float* __restrict__ h) {
  __shared__ float zs[32][NCH];
  __shared__ float w0as[NCH][HDIM];
  __shared__ float hs[32][129];
  int tid = threadIdx.x;
  int r0 = blockIdx.x * 32;

  for (int i = tid; i < NCH * HDIM; i += 256) w0as[i / HDIM][i % HDIM] = w0a[i];
  for (int i = tid; i < 32 * NCH; i += 256) {
    int r = i / NCH, c = i % NCH;
    int gr = r0 + r;
    zs[r][c] = (gr < N_NODES) ? z[gr * NCH + c] : 0.f;
  }
  __syncthreads();

  for (int i = tid; i < 32 * HDIM; i += 256) {
    int j = i & (HDIM - 1), r = i >> 7;
    float a = b0a[j];
#pragma unroll
    for (int c = 0; c < NCH; ++c) a += zs[r][c] * w0as[c][j];
    hs[r][j] = fmaxf(a, 0.f);
  }
  __syncthreads();

  int cg = tid & 31, rg = tid >> 5;
  int jb = cg * 4, r4 = rg * 4;
  float acc[4][4];
  tile_gemm(hs, w0b, b0b, r4, jb, acc);

#pragma unroll
  for (int ii = 0; ii < 4; ++ii) {
    int gr = r0 + r4 + ii;
    if (gr < N_NODES) {
      f4 o = {acc[ii][0], acc[ii][1], acc[ii][2], acc[ii][3]};
      *reinterpret_cast<f4*>(&h[gr * HDIM + jb]) = o;
    }
  }
}

// ---------------- edge gate: W = (relu(attr@w2a+b2a)@w2b + b2b) * C, bf16 -------

__global__ __launch_bounds__(256) void k_edge_gate(
    const float* __restrict__ attr, const float* __restrict__ elen,
    const float* __restrict__ w2a, const float* __restrict__ b2a,
    const float* __restrict__ w2b, const float* __restrict__ b2b,
    __hip_bfloat16* __restrict__ Wout) {
  __shared__ float as[32][129];
  __shared__ float hs[32][129];
  int tid = threadIdx.x;
  int e0 = blockIdx.x * 32;

  for (int i = tid; i < 32 * 32; i += 256) {
    int r = i >> 5, c4 = (i & 31) * 4;
    f4 v = *reinterpret_cast<const f4*>(&attr[(e0 + r) * HDIM + c4]);
    as[r][c4 + 0] = v[0];
    as[r][c4 + 1] = v[1];
    as[r][c4 + 2] = v[2];
    as[r][c4 + 3] = v[3];
  }
  __syncthreads();

  int cg = tid & 31, rg = tid >> 5;
  int jb = cg * 4, r4 = rg * 4;
  float acc[4][4];

  tile_gemm(as, w2a, b2a, r4, jb, acc);  // layer 1
#pragma unroll
  for (int ii = 0; ii < 4; ++ii)
#pragma unroll
    for (int jj = 0; jj < 4; ++jj) hs[r4 + ii][jb + jj] = fmaxf(acc[ii][jj], 0.f);
  __syncthreads();

  tile_gemm(hs, w2b, b2b, r4, jb, acc);  // layer 2

#pragma unroll
  for (int ii = 0; ii < 4; ++ii) {
    int e = e0 + r4 + ii;
    float msk = (elen[e] <= 10.0f) ? 1.0f : 0.0f;
    b16x4 o;
#pragma unroll
    for (int jj = 0; jj < 4; ++jj) o.v[jj] = __float2bfloat16(acc[ii][jj] * msk);
    *reinterpret_cast<b16x4*>(&Wout[e * HDIM + jb]) = o;
  }
}

// ---------------- aggregate: agg[n] = sum_{e: dst=n} relu(h[src]+W[e]) ---------

__global__ __launch_bounds__(256) void k_aggregate(
    const float* __restrict__ h, const __hip_bfloat16* __restrict__ W,
    const int* __restrict__ row, const int* __restrict__ eid,
    const int* __restrict__ esrc, float* __restrict__ agg) {
  int tid = threadIdx.x;
  int node = blockIdx.x * 8 + (tid >> 5);
  if (node >= N_NODES) return;
  int c4 = (tid & 31) * 4;
  int beg = row[node], end = row[node + 1];
  f4 s = {0.f, 0.f, 0.f, 0.f};
  for (int p = beg; p < end; ++p) {
    int e = eid[p];
    int sr = esrc[p];
    f4 hv = *reinterpret_cast<const f4*>(&h[sr * HDIM + c4]);
    b16x4 wv = *reinterpret_cast<const b16x4*>(&W[e * HDIM + c4]);
#pragma unroll
    for (int q = 0; q < 4; ++q) {
      float m = hv[q] + __bfloat162float(wv.v[q]);
      s[q] += fmaxf(m, 0.f);
    }
  }
  *reinterpret_cast<f4*>(&agg[node * HDIM + c4]) = s;
}

// ---------------- update: h += act(MLP1(agg + h)) ------------------------------

__global__ __launch_bounds__(256) void k_update(
    const float* __restrict__ agg, const float* __restrict__ w1a,
    const float* __restrict__ b1a, const float* __restrict__ w1b,
    const float* __restrict__ b1b, float* __restrict__ h, int relu_out) {
  __shared__ float as[32][129];
  __shared__ float hs[32][129];
  int tid = threadIdx.x;
  int r0 = blockIdx.x * 32;

  for (int i = tid; i < 32 * 32; i += 256) {
    int r = i >> 5, c4 = (i & 31) * 4;
    int gr = r0 + r;
    f4 v = {0.f, 0.f, 0.f, 0.f};
    if (gr < N_NODES) {
      f4 a = *reinterpret_cast<const f4*>(&agg[gr * HDIM + c4]);
      f4 hh = *reinterpret_cast<const f4*>(&h[gr * HDIM + c4]);
      v = a + hh;
    }
    as[r][c4 + 0] = v[0];
    as[r][c4 + 1] = v[1];
    as[r][c4 + 2] = v[2];
    as[r][c4 + 3] = v[3];
  }
  __syncthreads();

  int cg = tid & 31, rg = tid >> 5;
  int jb = cg * 4, r4 = rg * 4;
  float acc[4][4];

  tile_gemm(as, w1a, b1a, r4, jb, acc);  // layer 1
#pragma unroll
  for (int ii = 0; ii < 4; ++ii)
#pragma unroll
    for (int jj = 0; jj < 4; ++jj) hs[r4 + ii][jb + jj] = fmaxf(acc[ii][jj], 0.f);
  __syncthreads();

  tile_gemm(hs, w1b, b1b, r4, jb, acc);  // layer 2

#pragma unroll
  for (int ii = 0; ii < 4; ++ii) {
    int gr = r0 + r4 + ii;
    if (gr < N_NODES) {
      f4 hv = *reinterpret_cast<const f4*>(&h[gr * HDIM + jb]);
      f4 o;
#pragma unroll
      for (int jj = 0; jj < 4; ++jj) {
        float t = acc[ii][jj];
        if (relu_out) t = fmaxf(t, 0.f);
        o[jj] = hv[jj] + t;
      }
      *reinterpret_cast<f4*>(&h[gr * HDIM + jb]) = o;
    }
  }
}

// ---------------- launch --------------------------------------------------------

extern "C" void kernel_launch(void* const* d_in, const int* in_sizes, int n_in,
                              void* d_out, int out_size, void* d_ws, size_t ws_size,
                              hipStream_t stream) {
  const float* z = (const float*)d_in[0];
  const int* ei = (const int*)d_in[1];
  const float* attr = (const float*)d_in[2];
  const float* elen = (const float*)d_in[3];
  const float* w0a = (const float*)d_in[4];
  const float* b0a = (const float*)d_in[5];
  const float* w0b = (const float*)d_in[6];
  const float* b0b = (const float*)d_in[7];
  const float* w1a = (const float*)d_in[8];
  const float* b1a = (const float*)d_in[9];
  const float* w1b = (const float*)d_in[10];
  const float* b1b = (const float*)d_in[11];
  const float* w2a = (const float*)d_in[12];
  const float* b2a = (const float*)d_in[13];
  const float* w2b = (const float*)d_in[14];
  const float* b2b = (const float*)d_in[15];

  float* h = (float*)d_out;

  char* ws = (char*)d_ws;
  size_t off = 0;
  __hip_bfloat16* W = (__hip_bfloat16*)(ws + off);
  off += (size_t)N_EDGES * HDIM * 2;          // 204.8 MB
  float* agg = (float*)(ws + off);
  off += (size_t)N_NODES * HDIM * 4;          // 25.6 MB
  int* row = (int*)(ws + off);
  off += (size_t)(N_NODES + 1) * 4;
  int* cnt = (int*)(ws + off);
  off += (size_t)N_NODES * 4;
  int* cur = (int*)(ws + off);
  off += (size_t)N_NODES * 4;
  int* eid = (int*)(ws + off);
  off += (size_t)N_EDGES * 4;
  int* esrc = (int*)(ws + off);
  off += (size_t)N_EDGES * 4;                 // total ~237.4 MB

  const int* src = ei;
  const int* dst = ei + N_EDGES;

  hipMemsetAsync(cnt, 0, (size_t)N_NODES * 4, stream);
  k_count<<<(N_EDGES + 255) / 256, 256, 0, stream>>>(dst, cnt);
  k_scan<<<1, 256, 0, stream>>>(cnt, row, cur);
  k_scatter<<<(N_EDGES + 255) / 256, 256, 0, stream>>>(src, dst, cur, eid, esrc);

  k_node_emb<<<(N_NODES + 31) / 32, 256, 0, stream>>>(z, w0a, b0a, w0b, b0b, h);
  k_edge_gate<<<N_EDGES / 32, 256, 0, stream>>>(attr, elen, w2a, b2a, w2b, b2b, W);

  for (int conv = 0; conv < 3; ++conv) {
    k_aggregate<<<(N_NODES + 7) / 8, 256, 0, stream>>>(h, W, row, eid, esrc, agg);
    k_update<<<(N_NODES + 31) / 32, 256, 0, stream>>>(agg, w1a, b1a, w1b, b1b, h,
                                                      conv < 2 ? 1 : 0);
  }
}

// Round 2
// 955.010 us; speedup vs baseline: 1.7722x; 1.7722x over previous
//
#include <hip/hip_runtime.h>
#include <hip/hip_bf16.h>

#define N_NODES 50000
#define N_EDGES 800000
#define HDIM 128
#define NCH 5

typedef float f4 __attribute__((ext_vector_type(4)));
typedef short bf8 __attribute__((ext_vector_type(8)));    // 8 bf16 = MFMA A/B frag
typedef float f32x4 __attribute__((ext_vector_type(4)));  // MFMA C/D frag

struct __align__(8) b16x4 { __hip_bfloat16 v[4]; };
struct __align__(16) b16x8 { __hip_bfloat16 v[8]; };

// ---------------- CSR build ----------------

__global__ void k_count(const int* __restrict__ dst, int* __restrict__ cnt) {
  int i = blockIdx.x * blockDim.x + threadIdx.x;
  if (i < N_EDGES) atomicAdd(&cnt[dst[i]], 1);
}

__global__ void k_scan(const int* __restrict__ cnt, int* __restrict__ row,
                       int* __restrict__ cur) {
  __shared__ int buf[256];
  int tid = threadIdx.x;
  int run = 0;
  for (int base = 0; base < N_NODES; base += 256) {
    int i = base + tid;
    int v = (i < N_NODES) ? cnt[i] : 0;
    buf[tid] = v;
    __syncthreads();
    for (int off = 1; off < 256; off <<= 1) {
      int t = (tid >= off) ? buf[tid - off] : 0;
      __syncthreads();
      buf[tid] += t;
      __syncthreads();
    }
    if (i < N_NODES) {
      int excl = run + buf[tid] - v;
      row[i] = excl;
      cur[i] = excl;
    }
    run += buf[255];
    __syncthreads();
  }
  if (tid == 0) row[N_NODES] = run;
}

__global__ void k_scatter(const int* __restrict__ src, const int* __restrict__ dst,
                          int* __restrict__ cur, int* __restrict__ eid,
                          int* __restrict__ esrc) {
  int i = blockIdx.x * blockDim.x + threadIdx.x;
  if (i < N_EDGES) {
    int d = dst[i];
    int p = atomicAdd(&cur[d], 1);
    eid[p] = i;
    esrc[p] = src[i];
  }
}

// ---------------- weight repack for MFMA B-fragments ----------------
// wp[((jt*4+kk)*64 + l)*8 + j] = bf16( w[(kk*32 + (l>>4)*8 + j)*128 + jt*16 + (l&15)] )
// so a B-frag load in-kernel is one lane-contiguous 16B read (conflict/coalesce-perfect).

__global__ __launch_bounds__(256) void k_repack(const float* __restrict__ w,
                                                __hip_bfloat16* __restrict__ wp) {
  int idx = blockIdx.x * 256 + threadIdx.x;  // 0..2047
  int l = idx & 63;
  int f = idx >> 6;  // frag id = jt*4 + kk
  int kk = f & 3, jt = f >> 2;
  int col = jt * 16 + (l & 15);
  int kb = kk * 32 + (l >> 4) * 8;
  b16x8 o;
#pragma unroll
  for (int j = 0; j < 8; ++j) o.v[j] = __float2bfloat16(w[(kb + j) * HDIM + col]);
  *reinterpret_cast<b16x8*>(&wp[idx * 8]) = o;
}

// ---------------- shared f32 4x4-tile GEMM (kept for node_emb / update) --------

__device__ __forceinline__ void tile_gemm(const float (*in)[129],
                                          const float* __restrict__ wmat,
                                          const float* __restrict__ bias,
                                          int r4, int jb, float acc[4][4]) {
  f4 bv = *reinterpret_cast<const f4*>(&bias[jb]);
#pragma unroll
  for (int ii = 0; ii < 4; ++ii)
#pragma unroll
    for (int jj = 0; jj < 4; ++jj) acc[ii][jj] = bv[jj];
#pragma unroll 4
  for (int k = 0; k < HDIM; ++k) {
    f4 wv = *reinterpret_cast<const f4*>(&wmat[k * HDIM + jb]);
    float a0 = in[r4 + 0][k];
    float a1 = in[r4 + 1][k];
    float a2 = in[r4 + 2][k];
    float a3 = in[r4 + 3][k];
#pragma unroll
    for (int jj = 0; jj < 4; ++jj) {
      acc[0][jj] += a0 * wv[jj];
      acc[1][jj] += a1 * wv[jj];
      acc[2][jj] += a2 * wv[jj];
      acc[3][jj] += a3 * wv[jj];
    }
  }
}

// ---------------- node embedding: h = relu(z@w0a+b0a)@w0b + b0b ----------------

__global__ __launch_bounds__(256) void k_node_emb(
    const float* __restrict__ z, const float* __restrict__ w0a,
    const float* __restrict__ b0a, const float* __restrict__ w0b,
    const float* __restrict__ b0b, float* __restrict__ h) {
  __shared__ float zs[32][NCH];
  __shared__ float w0as[NCH][HDIM];
  __shared__ float hs[32][129];
  int tid = threadIdx.x;
  int r0 = blockIdx.x * 32;

  for (int i = tid; i < NCH * HDIM; i += 256) w0as[i / HDIM][i % HDIM] = w0a[i];
  for (int i = tid; i < 32 * NCH; i += 256) {
    int r = i / NCH, c = i % NCH;
    int gr = r0 + r;
    zs[r][c] = (gr < N_NODES) ? z[gr * NCH + c] : 0.f;
  }
  __syncthreads();

  for (int i = tid; i < 32 * HDIM; i += 256) {
    int j = i & (HDIM - 1), r = i >> 7;
    float a = b0a[j];
#pragma unroll
    for (int c = 0; c < NCH; ++c) a += zs[r][c] * w0as[c][j];
    hs[r][j] = fmaxf(a, 0.f);
  }
  __syncthreads();

  int cg = tid & 31, rg = tid >> 5;
  int jb = cg * 4, r4 = rg * 4;
  float acc[4][4];
  tile_gemm(hs, w0b, b0b, r4, jb, acc);

#pragma unroll
  for (int ii = 0; ii < 4; ++ii) {
    int gr = r0 + r4 + ii;
    if (gr < N_NODES) {
      f4 o = {acc[ii][0], acc[ii][1], acc[ii][2], acc[ii][3]};
      *reinterpret_cast<f4*>(&h[gr * HDIM + jb]) = o;
    }
  }
}

// ---------------- edge gate via MFMA: W = (relu(attr@w2a+b2a)@w2b + b2b)*C -----
// Block = 256 thr = 4 waves, 64 edges. Wave w owns output cols [32w, 32w+32).
// A staged in LDS as bf16 with XOR swizzle (byte ^= (row&7)<<4) so ds_read_b128
// A-fragment loads are bank-conflict-free. B frags live in registers (pre-packed).

#define SWZ(row, colByte) ((row) * 256 + ((colByte) ^ (((row) & 7) << 4)))

__global__ __launch_bounds__(256) void k_edge_gate_mfma(
    const float* __restrict__ attr, const float* __restrict__ elen,
    const __hip_bfloat16* __restrict__ w2aP, const float* __restrict__ b2a,
    const __hip_bfloat16* __restrict__ w2bP, const float* __restrict__ b2b,
    __hip_bfloat16* __restrict__ Wout) {
  __shared__ char sA[64 * 256];  // 64 x 128 bf16, swizzled
  __shared__ char sH[64 * 256];  // hidden, same layout
  __shared__ float sLen[64];
  const int tid = threadIdx.x;
  const int wv = tid >> 6, l = tid & 63;
  const int e0 = blockIdx.x * 64;

  if (tid < 64) sLen[tid] = elen[e0 + tid];

  // stage attr tile -> sA (f32 -> bf16), coalesced f4 loads
#pragma unroll
  for (int i = 0; i < 8; ++i) {
    int c = tid + i * 256;  // f4-chunk id, 2048 total
    int row = c >> 5, col4 = (c & 31) * 4;
    f4 v = *reinterpret_cast<const f4*>(&attr[(size_t)(e0 + row) * HDIM + col4]);
    b16x4 o;
    o.v[0] = __float2bfloat16(v[0]);
    o.v[1] = __float2bfloat16(v[1]);
    o.v[2] = __float2bfloat16(v[2]);
    o.v[3] = __float2bfloat16(v[3]);
    *reinterpret_cast<b16x4*>(&sA[SWZ(row, col4 * 2)]) = o;
  }

  // B fragments for both layers -> registers (16B coalesced, L2-resident)
  bf8 B1[2][4], B2[2][4];
#pragma unroll
  for (int nt = 0; nt < 2; ++nt)
#pragma unroll
    for (int kk = 0; kk < 4; ++kk) {
      int f = (2 * wv + nt) * 4 + kk;
      B1[nt][kk] = *reinterpret_cast<const bf8*>(&w2aP[(f * 64 + l) * 8]);
      B2[nt][kk] = *reinterpret_cast<const bf8*>(&w2bP[(f * 64 + l) * 8]);
    }

  __syncthreads();

  // ---- layer 1: hidden = relu(A @ w2a + b2a)
  f32x4 acc[4][2];
  float bias[2];
#pragma unroll
  for (int nt = 0; nt < 2; ++nt) bias[nt] = b2a[(2 * wv + nt) * 16 + (l & 15)];
#pragma unroll
  for (int mt = 0; mt < 4; ++mt)
#pragma unroll
    for (int nt = 0; nt < 2; ++nt)
      acc[mt][nt] = (f32x4){bias[nt], bias[nt], bias[nt], bias[nt]};

#pragma unroll
  for (int kk = 0; kk < 4; ++kk)
#pragma unroll
    for (int mt = 0; mt < 4; ++mt) {
      int row = mt * 16 + (l & 15);
      int kByte = (kk * 32 + (l >> 4) * 8) * 2;
      bf8 a = *reinterpret_cast<const bf8*>(&sA[SWZ(row, kByte)]);
#pragma unroll
      for (int nt = 0; nt < 2; ++nt)
        acc[mt][nt] = __builtin_amdgcn_mfma_f32_16x16x32_bf16(a, B1[nt][kk],
                                                              acc[mt][nt], 0, 0, 0);
    }

  // relu -> sH (bf16, swizzled). D layout: lane l reg i -> row (l>>4)*4+i, col l&15.
#pragma unroll
  for (int mt = 0; mt < 4; ++mt)
#pragma unroll
    for (int nt = 0; nt < 2; ++nt) {
      int colb = ((2 * wv + nt) * 16 + (l & 15)) * 2;
#pragma unroll
      for (int i = 0; i < 4; ++i) {
        int row = mt * 16 + (l >> 4) * 4 + i;
        *reinterpret_cast<__hip_bfloat16*>(&sH[SWZ(row, colb)]) =
            __float2bfloat16(fmaxf(acc[mt][nt][i], 0.f));
      }
    }
  __syncthreads();

  // ---- layer 2: out = hidden @ w2b + b2b
#pragma unroll
  for (int nt = 0; nt < 2; ++nt) bias[nt] = b2b[(2 * wv + nt) * 16 + (l & 15)];
#pragma unroll
  for (int mt = 0; mt < 4; ++mt)
#pragma unroll
    for (int nt = 0; nt < 2; ++nt)
      acc[mt][nt] = (f32x4){bias[nt], bias[nt], bias[nt], bias[nt]};

#pragma unroll
  for (int kk = 0; kk < 4; ++kk)
#pragma unroll
    for (int mt = 0; mt < 4; ++mt) {
      int row = mt * 16 + (l & 15);
      int kByte = (kk * 32 + (l >> 4) * 8) * 2;
      bf8 a = *reinterpret_cast<const bf8*>(&sH[SWZ(row, kByte)]);
#pragma unroll
      for (int nt = 0; nt < 2; ++nt)
        acc[mt][nt] = __builtin_amdgcn_mfma_f32_16x16x32_bf16(a, B2[nt][kk],
                                                              acc[mt][nt], 0, 0, 0);
    }

  // mask by cutoff, write bf16 back into sA (safe: all sA reads ended pre-sync2)
#pragma unroll
  for (int mt = 0; mt < 4; ++mt)
#pragma unroll
    for (int nt = 0; nt < 2; ++nt) {
      int colb = ((2 * wv + nt) * 16 + (l & 15)) * 2;
#pragma unroll
      for (int i = 0; i < 4; ++i) {
        int row = mt * 16 + (l >> 4) * 4 + i;
        float msk = (sLen[row] <= 10.0f) ? 1.0f : 0.0f;
        *reinterpret_cast<__hip_bfloat16*>(&sA[SWZ(row, colb)]) =
            __float2bfloat16(acc[mt][nt][i] * msk);
      }
    }
  __syncthreads();

  // coalesced 16B store of the 64x128 bf16 tile
#pragma unroll
  for (int i = 0; i < 4; ++i) {
    int c = tid + i * 256;  // 16B-chunk id, 1024 total
    int row = c >> 4, colc = c & 15;
    b16x8 v = *reinterpret_cast<const b16x8*>(&sA[SWZ(row, colc * 16)]);
    *reinterpret_cast<b16x8*>(&Wout[(size_t)(e0 + row) * HDIM + colc * 8]) = v;
  }
}

// ---------------- aggregate: agg[n] = sum_{e: dst=n} relu(h[src]+W[e]) ---------

__global__ __launch_bounds__(256) void k_aggregate(
    const float* __restrict__ h, const __hip_bfloat16* __restrict__ W,
    const int* __restrict__ row, const int* __restrict__ eid,
    const int* __restrict__ esrc, float* __restrict__ agg) {
  int tid = threadIdx.x;
  int node = blockIdx.x * 8 + (tid >> 5);
  if (node >= N_NODES) return;
  int c4 = (tid & 31) * 4;
  int beg = row[node], end = row[node + 1];
  f4 s = {0.f, 0.f, 0.f, 0.f};
  for (int p = beg; p < end; ++p) {
    int e = eid[p];
    int sr = esrc[p];
    f4 hv = *reinterpret_cast<const f4*>(&h[sr * HDIM + c4]);
    b16x4 wv = *reinterpret_cast<const b16x4*>(&W[e * HDIM + c4]);
#pragma unroll
    for (int q = 0; q < 4; ++q) {
      float m = hv[q] + __bfloat162float(wv.v[q]);
      s[q] += fmaxf(m, 0.f);
    }
  }
  *reinterpret_cast<f4*>(&agg[node * HDIM + c4]) = s;
}

// ---------------- update: h += act(MLP1(agg + h)) ------------------------------

__global__ __launch_bounds__(256) void k_update(
    const float* __restrict__ agg, const float* __restrict__ w1a,
    const float* __restrict__ b1a, const float* __restrict__ w1b,
    const float* __restrict__ b1b, float* __restrict__ h, int relu_out) {
  __shared__ float as[32][129];
  __shared__ float hs[32][129];
  int tid = threadIdx.x;
  int r0 = blockIdx.x * 32;

  for (int i = tid; i < 32 * 32; i += 256) {
    int r = i >> 5, c4 = (i & 31) * 4;
    int gr = r0 + r;
    f4 v = {0.f, 0.f, 0.f, 0.f};
    if (gr < N_NODES) {
      f4 a = *reinterpret_cast<const f4*>(&agg[gr * HDIM + c4]);
      f4 hh = *reinterpret_cast<const f4*>(&h[gr * HDIM + c4]);
      v = a + hh;
    }
    as[r][c4 + 0] = v[0];
    as[r][c4 + 1] = v[1];
    as[r][c4 + 2] = v[2];
    as[r][c4 + 3] = v[3];
  }
  __syncthreads();

  int cg = tid & 31, rg = tid >> 5;
  int jb = cg * 4, r4 = rg * 4;
  float acc[4][4];

  tile_gemm(as, w1a, b1a, r4, jb, acc);  // layer 1
#pragma unroll
  for (int ii = 0; ii < 4; ++ii)
#pragma unroll
    for (int jj = 0; jj < 4; ++jj) hs[r4 + ii][jb + jj] = fmaxf(acc[ii][jj], 0.f);
  __syncthreads();

  tile_gemm(hs, w1b, b1b, r4, jb, acc);  // layer 2

#pragma unroll
  for (int ii = 0; ii < 4; ++ii) {
    int gr = r0 + r4 + ii;
    if (gr < N_NODES) {
      f4 hv = *reinterpret_cast<const f4*>(&h[gr * HDIM + jb]);
      f4 o;
#pragma unroll
      for (int jj = 0; jj < 4; ++jj) {
        float t = acc[ii][jj];
        if (relu_out) t = fmaxf(t, 0.f);
        o[jj] = hv[jj] + t;
      }
      *reinterpret_cast<f4*>(&h[gr * HDIM + jb]) = o;
    }
  }
}

// ---------------- launch --------------------------------------------------------

extern "C" void kernel_launch(void* const* d_in, const int* in_sizes, int n_in,
                              void* d_out, int out_size, void* d_ws, size_t ws_size,
                              hipStream_t stream) {
  const float* z = (const float*)d_in[0];
  const int* ei = (const int*)d_in[1];
  const float* attr = (const float*)d_in[2];
  const float* elen = (const float*)d_in[3];
  const float* w0a = (const float*)d_in[4];
  const float* b0a = (const float*)d_in[5];
  const float* w0b = (const float*)d_in[6];
  const float* b0b = (const float*)d_in[7];
  const float* w1a = (const float*)d_in[8];
  const float* b1a = (const float*)d_in[9];
  const float* w1b = (const float*)d_in[10];
  const float* b1b = (const float*)d_in[11];
  const float* w2a = (const float*)d_in[12];
  const float* b2a = (const float*)d_in[13];
  const float* w2b = (const float*)d_in[14];
  const float* b2b = (const float*)d_in[15];

  float* h = (float*)d_out;

  char* ws = (char*)d_ws;
  size_t off = 0;
  __hip_bfloat16* W = (__hip_bfloat16*)(ws + off);
  off += (size_t)N_EDGES * HDIM * 2;  // 204.8 MB
  float* agg = (float*)(ws + off);
  off += (size_t)N_NODES * HDIM * 4;  // 25.6 MB
  int* row = (int*)(ws + off);
  off += (size_t)(N_NODES + 1) * 4;
  int* cnt = (int*)(ws + off);
  off += (size_t)N_NODES * 4;
  int* cur = (int*)(ws + off);
  off += (size_t)N_NODES * 4;
  int* eid = (int*)(ws + off);
  off += (size_t)N_EDGES * 4;
  int* esrc = (int*)(ws + off);
  off += (size_t)N_EDGES * 4;
  __hip_bfloat16* w2aP = (__hip_bfloat16*)(ws + off);
  off += (size_t)HDIM * HDIM * 2;  // 32 KB
  __hip_bfloat16* w2bP = (__hip_bfloat16*)(ws + off);
  off += (size_t)HDIM * HDIM * 2;  // 32 KB   (total ~237.5 MB)

  const int* src = ei;
  const int* dst = ei + N_EDGES;

  hipMemsetAsync(cnt, 0, (size_t)N_NODES * 4, stream);
  k_count<<<(N_EDGES + 255) / 256, 256, 0, stream>>>(dst, cnt);
  k_scan<<<1, 256, 0, stream>>>(cnt, row, cur);
  k_scatter<<<(N_EDGES + 255) / 256, 256, 0, stream>>>(src, dst, cur, eid, esrc);

  k_repack<<<8, 256, 0, stream>>>(w2a, w2aP);
  k_repack<<<8, 256, 0, stream>>>(w2b, w2bP);

  k_node_emb<<<(N_NODES + 31) / 32, 256, 0, stream>>>(z, w0a, b0a, w0b, b0b, h);
  k_edge_gate_mfma<<<N_EDGES / 64, 256, 0, stream>>>(attr, elen, w2aP, b2a, w2bP,
                                                     b2b, W);

  for (int conv = 0; conv < 3; ++conv) {
    k_aggregate<<<(N_NODES + 7) / 8, 256, 0, stream>>>(h, W, row, eid, esrc, agg);
    k_update<<<(N_NODES + 31) / 32, 256, 0, stream>>>(agg, w1a, b1a, w1b, b1b, h,
                                                      conv < 2 ? 1 : 0);
  }
}

// Round 3
// 618.432 us; speedup vs baseline: 2.7368x; 1.5442x over previous
//
#include <hip/hip_runtime.h>
#include <hip/hip_bf16.h>

#define N_NODES 50000
#define N_EDGES 800000
#define HDIM 128
#define NCH 5
#define NB_SCAN ((N_NODES + 255) / 256)  // 196

typedef float f4 __attribute__((ext_vector_type(4)));
typedef short bf8 __attribute__((ext_vector_type(8)));    // 8 bf16 = MFMA A/B frag
typedef float f32x4 __attribute__((ext_vector_type(4)));  // MFMA C/D frag

struct __align__(8) b16x4 { __hip_bfloat16 v[4]; };
struct __align__(16) b16x8 { __hip_bfloat16 v[8]; };

// ---------------- CSR build ----------------

__global__ void k_count(const int* __restrict__ dst, int* __restrict__ cnt) {
  int i = blockIdx.x * blockDim.x + threadIdx.x;
  if (i < N_EDGES) atomicAdd(&cnt[dst[i]], 1);
}

// 3-phase multi-block exclusive scan of cnt -> row (+cur copy)
__global__ __launch_bounds__(256) void k_scan_local(const int* __restrict__ cnt,
                                                    int* __restrict__ row,
                                                    int* __restrict__ bsum) {
  __shared__ int buf[256];
  int b = blockIdx.x, tid = threadIdx.x, i = b * 256 + tid;
  int v = (i < N_NODES) ? cnt[i] : 0;
  buf[tid] = v;
  __syncthreads();
  for (int off = 1; off < 256; off <<= 1) {
    int t = (tid >= off) ? buf[tid - off] : 0;
    __syncthreads();
    buf[tid] += t;
    __syncthreads();
  }
  if (i < N_NODES) row[i] = buf[tid] - v;  // local exclusive
  if (tid == 255) bsum[b] = buf[255];
}

__global__ __launch_bounds__(256) void k_scan_top(const int* __restrict__ bsum,
                                                  int* __restrict__ boff) {
  __shared__ int buf[256];
  int tid = threadIdx.x;
  int v = (tid < NB_SCAN) ? bsum[tid] : 0;
  buf[tid] = v;
  __syncthreads();
  for (int off = 1; off < 256; off <<= 1) {
    int t = (tid >= off) ? buf[tid - off] : 0;
    __syncthreads();
    buf[tid] += t;
    __syncthreads();
  }
  if (tid < NB_SCAN) boff[tid] = buf[tid] - v;
  if (tid == 255) boff[NB_SCAN] = buf[255];  // grand total
}

__global__ __launch_bounds__(256) void k_scan_add(int* __restrict__ row,
                                                  const int* __restrict__ boff,
                                                  int* __restrict__ cur) {
  int b = blockIdx.x, tid = threadIdx.x, i = b * 256 + tid;
  if (i < N_NODES) {
    int r = row[i] + boff[b];
    row[i] = r;
    cur[i] = r;
  }
  if (b == 0 && tid == 0) row[N_NODES] = boff[NB_SCAN];
}

// pos[e] = CSR slot of edge e; esrc[slot] = src of that edge
__global__ void k_scatter(const int* __restrict__ src, const int* __restrict__ dst,
                          int* __restrict__ cur, int* __restrict__ pos,
                          int* __restrict__ esrc) {
  int i = blockIdx.x * blockDim.x + threadIdx.x;
  if (i < N_EDGES) {
    int d = dst[i];
    int p = atomicAdd(&cur[d], 1);
    pos[i] = p;
    esrc[p] = src[i];
  }
}

// ---------------- weight repack for MFMA B-fragments ----------------
// wp[((jt*4+kk)*64 + l)*8 + j] = bf16( w[(kk*32 + (l>>4)*8 + j)*128 + jt*16 + (l&15)] )

__global__ __launch_bounds__(256) void k_repack(const float* __restrict__ w,
                                                __hip_bfloat16* __restrict__ wp) {
  int idx = blockIdx.x * 256 + threadIdx.x;  // 0..2047
  int l = idx & 63;
  int f = idx >> 6;  // frag id = jt*4 + kk
  int kk = f & 3, jt = f >> 2;
  int col = jt * 16 + (l & 15);
  int kb = kk * 32 + (l >> 4) * 8;
  b16x8 o;
#pragma unroll
  for (int j = 0; j < 8; ++j) o.v[j] = __float2bfloat16(w[(kb + j) * HDIM + col]);
  *reinterpret_cast<b16x8*>(&wp[idx * 8]) = o;
}

// ---------------- shared f32 4x4-tile GEMM (node_emb only) --------

__device__ __forceinline__ void tile_gemm(const float (*in)[129],
                                          const float* __restrict__ wmat,
                                          const float* __restrict__ bias,
                                          int r4, int jb, float acc[4][4]) {
  f4 bv = *reinterpret_cast<const f4*>(&bias[jb]);
#pragma unroll
  for (int ii = 0; ii < 4; ++ii)
#pragma unroll
    for (int jj = 0; jj < 4; ++jj) acc[ii][jj] = bv[jj];
#pragma unroll 4
  for (int k = 0; k < HDIM; ++k) {
    f4 wv = *reinterpret_cast<const f4*>(&wmat[k * HDIM + jb]);
    float a0 = in[r4 + 0][k];
    float a1 = in[r4 + 1][k];
    float a2 = in[r4 + 2][k];
    float a3 = in[r4 + 3][k];
#pragma unroll
    for (int jj = 0; jj < 4; ++jj) {
      acc[0][jj] += a0 * wv[jj];
      acc[1][jj] += a1 * wv[jj];
      acc[2][jj] += a2 * wv[jj];
      acc[3][jj] += a3 * wv[jj];
    }
  }
}

// ---------------- node embedding: h = relu(z@w0a+b0a)@w0b + b0b ----------------

__global__ __launch_bounds__(256) void k_node_emb(
    const float* __restrict__ z, const float* __restrict__ w0a,
    const float* __restrict__ b0a, const float* __restrict__ w0b,
    const float* __restrict__ b0b, float* __restrict__ h) {
  __shared__ float zs[32][NCH];
  __shared__ float w0as[NCH][HDIM];
  __shared__ float hs[32][129];
  int tid = threadIdx.x;
  int r0 = blockIdx.x * 32;

  for (int i = tid; i < NCH * HDIM; i += 256) w0as[i / HDIM][i % HDIM] = w0a[i];
  for (int i = tid; i < 32 * NCH; i += 256) {
    int r = i / NCH, c = i % NCH;
    int gr = r0 + r;
    zs[r][c] = (gr < N_NODES) ? z[gr * NCH + c] : 0.f;
  }
  __syncthreads();

  for (int i = tid; i < 32 * HDIM; i += 256) {
    int j = i & (HDIM - 1), r = i >> 7;
    float a = b0a[j];
#pragma unroll
    for (int c = 0; c < NCH; ++c) a += zs[r][c] * w0as[c][j];
    hs[r][j] = fmaxf(a, 0.f);
  }
  __syncthreads();

  int cg = tid & 31, rg = tid >> 5;
  int jb = cg * 4, r4 = rg * 4;
  float acc[4][4];
  tile_gemm(hs, w0b, b0b, r4, jb, acc);

#pragma unroll
  for (int ii = 0; ii < 4; ++ii) {
    int gr = r0 + r4 + ii;
    if (gr < N_NODES) {
      f4 o = {acc[ii][0], acc[ii][1], acc[ii][2], acc[ii][3]};
      *reinterpret_cast<f4*>(&h[gr * HDIM + jb]) = o;
    }
  }
}

// ---------------- edge gate via MFMA, output permuted to CSR slots ------------
// Block = 256 thr = 4 waves, 64 edges. Wave w owns output cols [32w, 32w+32).

#define SWZ(row, colByte) ((row) * 256 + ((colByte) ^ (((row) & 7) << 4)))

__global__ __launch_bounds__(256) void k_edge_gate_mfma(
    const float* __restrict__ attr, const float* __restrict__ elen,
    const __hip_bfloat16* __restrict__ w2aP, const float* __restrict__ b2a,
    const __hip_bfloat16* __restrict__ w2bP, const float* __restrict__ b2b,
    const int* __restrict__ pos, __hip_bfloat16* __restrict__ Wp) {
  __shared__ char sA[64 * 256];  // 64 x 128 bf16, swizzled
  __shared__ char sH[64 * 256];  // hidden, same layout
  __shared__ float sLen[64];
  __shared__ int sPos[64];
  const int tid = threadIdx.x;
  const int wv = tid >> 6, l = tid & 63;
  const int e0 = blockIdx.x * 64;

  if (tid < 64) {
    sLen[tid] = elen[e0 + tid];
    sPos[tid] = pos[e0 + tid];
  }

  // stage attr tile -> sA (f32 -> bf16), coalesced f4 loads
#pragma unroll
  for (int i = 0; i < 8; ++i) {
    int c = tid + i * 256;  // f4-chunk id, 2048 total
    int row = c >> 5, col4 = (c & 31) * 4;
    f4 v = *reinterpret_cast<const f4*>(&attr[(size_t)(e0 + row) * HDIM + col4]);
    b16x4 o;
    o.v[0] = __float2bfloat16(v[0]);
    o.v[1] = __float2bfloat16(v[1]);
    o.v[2] = __float2bfloat16(v[2]);
    o.v[3] = __float2bfloat16(v[3]);
    *reinterpret_cast<b16x4*>(&sA[SWZ(row, col4 * 2)]) = o;
  }

  // B fragments for both layers -> registers
  bf8 B1[2][4], B2[2][4];
#pragma unroll
  for (int nt = 0; nt < 2; ++nt)
#pragma unroll
    for (int kk = 0; kk < 4; ++kk) {
      int f = (2 * wv + nt) * 4 + kk;
      B1[nt][kk] = *reinterpret_cast<const bf8*>(&w2aP[(f * 64 + l) * 8]);
      B2[nt][kk] = *reinterpret_cast<const bf8*>(&w2bP[(f * 64 + l) * 8]);
    }

  __syncthreads();

  // ---- layer 1: hidden = relu(A @ w2a + b2a)
  f32x4 acc[4][2];
  float bias[2];
#pragma unroll
  for (int nt = 0; nt < 2; ++nt) bias[nt] = b2a[(2 * wv + nt) * 16 + (l & 15)];
#pragma unroll
  for (int mt = 0; mt < 4; ++mt)
#pragma unroll
    for (int nt = 0; nt < 2; ++nt)
      acc[mt][nt] = (f32x4){bias[nt], bias[nt], bias[nt], bias[nt]};

#pragma unroll
  for (int kk = 0; kk < 4; ++kk)
#pragma unroll
    for (int mt = 0; mt < 4; ++mt) {
      int row = mt * 16 + (l & 15);
      int kByte = (kk * 32 + (l >> 4) * 8) * 2;
      bf8 a = *reinterpret_cast<const bf8*>(&sA[SWZ(row, kByte)]);
#pragma unroll
      for (int nt = 0; nt < 2; ++nt)
        acc[mt][nt] = __builtin_amdgcn_mfma_f32_16x16x32_bf16(a, B1[nt][kk],
                                                              acc[mt][nt], 0, 0, 0);
    }

  // relu -> sH (bf16, swizzled). D layout: lane l reg i -> row (l>>4)*4+i, col l&15.
#pragma unroll
  for (int mt = 0; mt < 4; ++mt)
#pragma unroll
    for (int nt = 0; nt < 2; ++nt) {
      int colb = ((2 * wv + nt) * 16 + (l & 15)) * 2;
#pragma unroll
      for (int i = 0; i < 4; ++i) {
        int row = mt * 16 + (l >> 4) * 4 + i;
        *reinterpret_cast<__hip_bfloat16*>(&sH[SWZ(row, colb)]) =
            __float2bfloat16(fmaxf(acc[mt][nt][i], 0.f));
      }
    }
  __syncthreads();

  // ---- layer 2: out = hidden @ w2b + b2b
#pragma unroll
  for (int nt = 0; nt < 2; ++nt) bias[nt] = b2b[(2 * wv + nt) * 16 + (l & 15)];
#pragma unroll
  for (int mt = 0; mt < 4; ++mt)
#pragma unroll
    for (int nt = 0; nt < 2; ++nt)
      acc[mt][nt] = (f32x4){bias[nt], bias[nt], bias[nt], bias[nt]};

#pragma unroll
  for (int kk = 0; kk < 4; ++kk)
#pragma unroll
    for (int mt = 0; mt < 4; ++mt) {
      int row = mt * 16 + (l & 15);
      int kByte = (kk * 32 + (l >> 4) * 8) * 2;
      bf8 a = *reinterpret_cast<const bf8*>(&sH[SWZ(row, kByte)]);
#pragma unroll
      for (int nt = 0; nt < 2; ++nt)
        acc[mt][nt] = __builtin_amdgcn_mfma_f32_16x16x32_bf16(a, B2[nt][kk],
                                                              acc[mt][nt], 0, 0, 0);
    }

  // mask by cutoff, write bf16 back into sA
#pragma unroll
  for (int mt = 0; mt < 4; ++mt)
#pragma unroll
    for (int nt = 0; nt < 2; ++nt) {
      int colb = ((2 * wv + nt) * 16 + (l & 15)) * 2;
#pragma unroll
      for (int i = 0; i < 4; ++i) {
        int row = mt * 16 + (l >> 4) * 4 + i;
        float msk = (sLen[row] <= 10.0f) ? 1.0f : 0.0f;
        *reinterpret_cast<__hip_bfloat16*>(&sA[SWZ(row, colb)]) =
            __float2bfloat16(acc[mt][nt][i] * msk);
      }
    }
  __syncthreads();

  // store rows to their CSR slots (256 B contiguous per row)
#pragma unroll
  for (int i = 0; i < 4; ++i) {
    int c = tid + i * 256;  // 16B-chunk id, 1024 total
    int row = c >> 4, colc = c & 15;
    b16x8 v = *reinterpret_cast<const b16x8*>(&sA[SWZ(row, colc * 16)]);
    *reinterpret_cast<b16x8*>(&Wp[(size_t)sPos[row] * HDIM + colc * 8]) = v;
  }
}

// ---------------- aggregate: agg[n] = sum_{p in CSR[n]} relu(h[esrc[p]]+Wp[p]) --

__global__ __launch_bounds__(256) void k_aggregate(
    const float* __restrict__ h, const __hip_bfloat16* __restrict__ Wp,
    const int* __restrict__ row, const int* __restrict__ esrc,
    float* __restrict__ agg) {
  int tid = threadIdx.x;
  int node = blockIdx.x * 8 + (tid >> 5);
  if (node >= N_NODES) return;
  int c4 = (tid & 31) * 4;
  int beg = row[node], end = row[node + 1];
  f4 s = {0.f, 0.f, 0.f, 0.f};
  for (int p = beg; p < end; ++p) {
    int sr = esrc[p];
    f4 hv = *reinterpret_cast<const f4*>(&h[(size_t)sr * HDIM + c4]);
    b16x4 wv = *reinterpret_cast<const b16x4*>(&Wp[(size_t)p * HDIM + c4]);
#pragma unroll
    for (int q = 0; q < 4; ++q) {
      float m = hv[q] + __bfloat162float(wv.v[q]);
      s[q] += fmaxf(m, 0.f);
    }
  }
  *reinterpret_cast<f4*>(&agg[(size_t)node * HDIM + c4]) = s;
}

// ---------------- update via MFMA: h += act(MLP1(agg + h)) ---------------------
// Same 64-row / 4-wave structure as the edge gate.

__global__ __launch_bounds__(256) void k_update_mfma(
    const float* __restrict__ agg, const __hip_bfloat16* __restrict__ w1aP,
    const float* __restrict__ b1a, const __hip_bfloat16* __restrict__ w1bP,
    const float* __restrict__ b1b, float* __restrict__ h, int relu_out) {
  __shared__ char sA[64 * 256];  // 64 x 128 bf16 (agg+h), swizzled
  __shared__ char sH[64 * 256];  // hidden
  const int tid = threadIdx.x;
  const int wv = tid >> 6, l = tid & 63;
  const int r0 = blockIdx.x * 64;

  // stage (agg + h) -> sA bf16
#pragma unroll
  for (int i = 0; i < 8; ++i) {
    int c = tid + i * 256;
    int row = c >> 5, col4 = (c & 31) * 4;
    int gr = r0 + row;
    f4 v = {0.f, 0.f, 0.f, 0.f};
    if (gr < N_NODES) {
      f4 a = *reinterpret_cast<const f4*>(&agg[(size_t)gr * HDIM + col4]);
      f4 hh = *reinterpret_cast<const f4*>(&h[(size_t)gr * HDIM + col4]);
      v = a + hh;
    }
    b16x4 o;
    o.v[0] = __float2bfloat16(v[0]);
    o.v[1] = __float2bfloat16(v[1]);
    o.v[2] = __float2bfloat16(v[2]);
    o.v[3] = __float2bfloat16(v[3]);
    *reinterpret_cast<b16x4*>(&sA[SWZ(row, col4 * 2)]) = o;
  }

  bf8 B1[2][4], B2[2][4];
#pragma unroll
  for (int nt = 0; nt < 2; ++nt)
#pragma unroll
    for (int kk = 0; kk < 4; ++kk) {
      int f = (2 * wv + nt) * 4 + kk;
      B1[nt][kk] = *reinterpret_cast<const bf8*>(&w1aP[(f * 64 + l) * 8]);
      B2[nt][kk] = *reinterpret_cast<const bf8*>(&w1bP[(f * 64 + l) * 8]);
    }

  __syncthreads();

  // layer 1
  f32x4 acc[4][2];
  float bias[2];
#pragma unroll
  for (int nt = 0; nt < 2; ++nt) bias[nt] = b1a[(2 * wv + nt) * 16 + (l & 15)];
#pragma unroll
  for (int mt = 0; mt < 4; ++mt)
#pragma unroll
    for (int nt = 0; nt < 2; ++nt)
      acc[mt][nt] = (f32x4){bias[nt], bias[nt], bias[nt], bias[nt]};

#pragma unroll
  for (int kk = 0; kk < 4; ++kk)
#pragma unroll
    for (int mt = 0; mt < 4; ++mt) {
      int row = mt * 16 + (l & 15);
      int kByte = (kk * 32 + (l >> 4) * 8) * 2;
      bf8 a = *reinterpret_cast<const bf8*>(&sA[SWZ(row, kByte)]);
#pragma unroll
      for (int nt = 0; nt < 2; ++nt)
        acc[mt][nt] = __builtin_amdgcn_mfma_f32_16x16x32_bf16(a, B1[nt][kk],
                                                              acc[mt][nt], 0, 0, 0);
    }

#pragma unroll
  for (int mt = 0; mt < 4; ++mt)
#pragma unroll
    for (int nt = 0; nt < 2; ++nt) {
      int colb = ((2 * wv + nt) * 16 + (l & 15)) * 2;
#pragma unroll
      for (int i = 0; i < 4; ++i) {
        int row = mt * 16 + (l >> 4) * 4 + i;
        *reinterpret_cast<__hip_bfloat16*>(&sH[SWZ(row, colb)]) =
            __float2bfloat16(fmaxf(acc[mt][nt][i], 0.f));
      }
    }
  __syncthreads();

  // layer 2
#pragma unroll
  for (int nt = 0; nt < 2; ++nt) bias[nt] = b1b[(2 * wv + nt) * 16 + (l & 15)];
#pragma unroll
  for (int mt = 0; mt < 4; ++mt)
#pragma unroll
    for (int nt = 0; nt < 2; ++nt)
      acc[mt][nt] = (f32x4){bias[nt], bias[nt], bias[nt], bias[nt]};

#pragma unroll
  for (int kk = 0; kk < 4; ++kk)
#pragma unroll
    for (int mt = 0; mt < 4; ++mt) {
      int row = mt * 16 + (l & 15);
      int kByte = (kk * 32 + (l >> 4) * 8) * 2;
      bf8 a = *reinterpret_cast<const bf8*>(&sH[SWZ(row, kByte)]);
#pragma unroll
      for (int nt = 0; nt < 2; ++nt)
        acc[mt][nt] = __builtin_amdgcn_mfma_f32_16x16x32_bf16(a, B2[nt][kk],
                                                              acc[mt][nt], 0, 0, 0);
    }

  // epilogue: h += act(out)   (f32 RMW, 64 B segments per 16-lane group, L2-warm)
#pragma unroll
  for (int mt = 0; mt < 4; ++mt)
#pragma unroll
    for (int nt = 0; nt < 2; ++nt) {
      int col = (2 * wv + nt) * 16 + (l & 15);
#pragma unroll
      for (int i = 0; i < 4; ++i) {
        int row = mt * 16 + (l >> 4) * 4 + i;
        int gr = r0 + row;
        if (gr < N_NODES) {
          float t = acc[mt][nt][i];
          if (relu_out) t = fmaxf(t, 0.f);
          size_t idx = (size_t)gr * HDIM + col;
          h[idx] = h[idx] + t;
        }
      }
    }
}

// ---------------- launch --------------------------------------------------------

extern "C" void kernel_launch(void* const* d_in, const int* in_sizes, int n_in,
                              void* d_out, int out_size, void* d_ws, size_t ws_size,
                              hipStream_t stream) {
  const float* z = (const float*)d_in[0];
  const int* ei = (const int*)d_in[1];
  const float* attr = (const float*)d_in[2];
  const float* elen = (const float*)d_in[3];
  const float* w0a = (const float*)d_in[4];
  const float* b0a = (const float*)d_in[5];
  const float* w0b = (const float*)d_in[6];
  const float* b0b = (const float*)d_in[7];
  const float* w1a = (const float*)d_in[8];
  const float* b1a = (const float*)d_in[9];
  const float* w1b = (const float*)d_in[10];
  const float* b1b = (const float*)d_in[11];
  const float* w2a = (const float*)d_in[12];
  const float* b2a = (const float*)d_in[13];
  const float* w2b = (const float*)d_in[14];
  const float* b2b = (const float*)d_in[15];

  float* h = (float*)d_out;

  char* ws = (char*)d_ws;
  size_t off = 0;
  __hip_bfloat16* Wp = (__hip_bfloat16*)(ws + off);
  off += (size_t)N_EDGES * HDIM * 2;  // 204.8 MB
  float* agg = (float*)(ws + off);
  off += (size_t)N_NODES * HDIM * 4;  // 25.6 MB
  int* row = (int*)(ws + off);
  off += (size_t)(N_NODES + 64) * 4;
  int* cnt = (int*)(ws + off);
  off += (size_t)N_NODES * 4;
  int* cur = (int*)(ws + off);
  off += (size_t)N_NODES * 4;
  int* pos = (int*)(ws + off);
  off += (size_t)N_EDGES * 4;
  int* esrc = (int*)(ws + off);
  off += (size_t)N_EDGES * 4;
  int* bsum = (int*)(ws + off);
  off += (size_t)(NB_SCAN + 8) * 4;
  int* boff = (int*)(ws + off);
  off += (size_t)(NB_SCAN + 8) * 4;
  __hip_bfloat16* w2aP = (__hip_bfloat16*)(ws + off);
  off += (size_t)HDIM * HDIM * 2;
  __hip_bfloat16* w2bP = (__hip_bfloat16*)(ws + off);
  off += (size_t)HDIM * HDIM * 2;
  __hip_bfloat16* w1aP = (__hip_bfloat16*)(ws + off);
  off += (size_t)HDIM * HDIM * 2;
  __hip_bfloat16* w1bP = (__hip_bfloat16*)(ws + off);
  off += (size_t)HDIM * HDIM * 2;  // total ~237.6 MB

  const int* src = ei;
  const int* dst = ei + N_EDGES;

  hipMemsetAsync(cnt, 0, (size_t)N_NODES * 4, stream);
  k_count<<<(N_EDGES + 255) / 256, 256, 0, stream>>>(dst, cnt);
  k_scan_local<<<NB_SCAN, 256, 0, stream>>>(cnt, row, bsum);
  k_scan_top<<<1, 256, 0, stream>>>(bsum, boff);
  k_scan_add<<<NB_SCAN, 256, 0, stream>>>(row, boff, cur);
  k_scatter<<<(N_EDGES + 255) / 256, 256, 0, stream>>>(src, dst, cur, pos, esrc);

  k_repack<<<8, 256, 0, stream>>>(w2a, w2aP);
  k_repack<<<8, 256, 0, stream>>>(w2b, w2bP);
  k_repack<<<8, 256, 0, stream>>>(w1a, w1aP);
  k_repack<<<8, 256, 0, stream>>>(w1b, w1bP);

  k_node_emb<<<(N_NODES + 31) / 32, 256, 0, stream>>>(z, w0a, b0a, w0b, b0b, h);
  k_edge_gate_mfma<<<N_EDGES / 64, 256, 0, stream>>>(attr, elen, w2aP, b2a, w2bP,
                                                     b2b, pos, Wp);

  for (int conv = 0; conv < 3; ++conv) {
    k_aggregate<<<(N_NODES + 7) / 8, 256, 0, stream>>>(h, Wp, row, esrc, agg);
    k_update_mfma<<<(N_NODES + 63) / 64, 256, 0, stream>>>(agg, w1aP, b1a, w1bP,
                                                           b1b, h, conv < 2 ? 1 : 0);
  }
}